// Round 6
// baseline (606.458 us; speedup 1.0000x reference)
//
#include <hip/hip_runtime.h>
#include <cstdint>

typedef unsigned short u16;
typedef __attribute__((ext_vector_type(8))) short short8;   // 8 bf16 (4 VGPRs)
typedef __attribute__((ext_vector_type(4))) float floatx4;  // MFMA C/D
typedef __attribute__((ext_vector_type(4))) float f32x4;
typedef __attribute__((ext_vector_type(8))) u16 u16x8;

static constexpr int K_DIM = 4096;
static constexpr int N_DIM = 11008;
static constexpr int NPACK = 1376;  // N/8
static constexpr int GSIZE = 128;
static constexpr int NGRP = 32;     // K/GSIZE

// fp32 -> bf16 round-to-nearest-even (raw bits)
__device__ __forceinline__ u16 f2bf(float f) {
  uint32_t u = __builtin_bit_cast(uint32_t, f);
  u += 0x7FFFu + ((u >> 16) & 1u);
  return (u16)(u >> 16);
}

// async global->LDS, 16B per lane, dest = wave-uniform base + lane*16
__device__ __forceinline__ void async16(const void* g, void* l) {
  __builtin_amdgcn_global_load_lds(
      (const __attribute__((address_space(1))) void*)g,
      (__attribute__((address_space(3))) void*)l, 16, 0, 0);
}

// ---------------------------------------------------------------------------
// x fp32 [M,K] -> bf16 [M,K]; one thread = 8 elements (16B in, 16B out)
__global__ void cvt_x_bf16(const float* __restrict__ x, u16* __restrict__ xb) {
  int t = blockIdx.x * 256 + threadIdx.x;
  const f32x4* xv = (const f32x4*)x;
  f32x4 a = xv[2 * t];
  f32x4 b = xv[2 * t + 1];
  u16x8 o;
  o[0] = f2bf(a[0]); o[1] = f2bf(a[1]); o[2] = f2bf(a[2]); o[3] = f2bf(a[3]);
  o[4] = f2bf(b[0]); o[5] = f2bf(b[1]); o[6] = f2bf(b[2]); o[7] = f2bf(b[3]);
  ((u16x8*)xb)[t] = o;
}

// ---------------------------------------------------------------------------
// qweight [K, N/8] int32 -> Wt [N, K] bf16 (dequantized, TRANSPOSED)
// v3 stores (R4, measured ~neutral vs v0; kept): lane l -> (n = c*8 +
// (l>>3), k = kk*64 + (l&7)*8); 16B per store, each 8-lane group 128B
// contiguous (full lines, no write amplification).
__global__ __launch_bounds__(256) void dequant_wt(
    const int* __restrict__ qw, const int* __restrict__ qz,
    const float* __restrict__ sc, u16* __restrict__ Wt) {
  constexpr int KT = 128, PT = 32, LSTR = PT + 1;
  __shared__ int pk[KT * LSTR];   // 16.5 KB, [k][p] padded
  __shared__ float scs[PT * 8];   // 1 KB
  __shared__ int zs[PT];

  const int tid = threadIdx.x;
  const int p0 = blockIdx.x * PT;   // 43 blocks
  const int k0 = blockIdx.y * KT;   // 32 blocks
  const int g = k0 >> 7;            // KT == GSIZE: one group per tile

#pragma unroll
  for (int i = 0; i < 16; i++) {    // 4096 ints, coalesced (128B rows)
    int idx = tid + i * 256;
    int r = idx >> 5, c = idx & 31;
    pk[r * LSTR + c] = qw[(size_t)(k0 + r) * NPACK + p0 + c];
  }
  if (tid < PT) zs[tid] = qz[g * NPACK + p0 + tid];
  if (tid < PT * 8) scs[tid] = sc[(size_t)g * N_DIM + p0 * 8 + tid];
  __syncthreads();

  const int wave = tid >> 6, lane = tid & 63;
  const int j = lane >> 3;                       // n-position in packed int
  const int kb = (lane & 7) * 8;                 // k-offset of this lane's 8k
  const int sh = ((j & 1) << 4) | ((j >> 1) << 2);  // 0,16,4,20,8,24,12,28

#pragma unroll 2
  for (int ci = 0; ci < 8; ci++) {
    const int c = wave * 8 + ci;                 // packed col 0..31
    const int zv = (zs[c] >> sh) & 15;
    const float s = scs[c * 8 + j];
    u16* op = Wt + (size_t)(p0 * 8 + c * 8 + j) * K_DIM + k0 + kb;
#pragma unroll
    for (int kk = 0; kk < 2; kk++) {
      const int kbase = kk * 64 + kb;
      u16x8 o;
#pragma unroll
      for (int e = 0; e < 8; e++) {
        int q = pk[(kbase + e) * LSTR + c];
        o[e] = f2bf((float)(((q >> sh) & 15) - zv) * s);
      }
      *(u16x8*)(op + kk * 64) = o;
    }
  }
}

// ---------------------------------------------------------------------------
// C[M,N] = A[M,K] * Bt[N,K]^T + bias ; bf16 in, fp32 out.
// v6 = v1 (measured 357us, MfmaUtil 47.6, conflicts 0) + HALF-TILE GATING:
// LDS is organized as K-major units: U0 = {A,B}[all 256 rows][k 0..31],
// U1 = k 32..63. Phases ph0/ph1 consume only U0, ph2/ph3 only U1, so the
// single whole-tile gate (vmcnt(2), 8-load wait) splits into two vmcnt(4)
// gates, each draining only the half about to be consumed while the other
// half + next prefetch (4 loads) stay in flight. Issue points: t+1:U0
// during ph0/ph1, t+1:U1 during ph2/ph3 -> every unit gets ~4 phases
// (~2000cy) of landing margin (v1 worst case: ~1 phase).
// Ring hazard: t+1:U0 overwrites t-1:U0, last read in t-1's ph1, >=4
// barriers earlier — safe. Swizzle: same both-sides XOR involution family,
// now 2-bit over 4 chunks/32-elem row (phys = logical ^ (row&3)); bank
// walk: 8 lanes per 4-bank group, balanced (same proof as v1's 3-bit
// variant that measured 0 conflicts). VGPR budget unchanged (112).
__global__ __launch_bounds__(512, 2) void gemm_bf16_256(
    const u16* __restrict__ A, const u16* __restrict__ Bt,
    const float* __restrict__ bias, float* __restrict__ out, int Mb) {
  constexpr int NT = K_DIM / 64;              // 64 K-tiles
  // [2 buf][U0: A 8192 | B 8192][U1: A 8192 | B 8192]  (elems) = 128 KB
  __shared__ __align__(16) u16 lds[65536];

  const int f = blockIdx.x;
  int mb, nb;
  if ((Mb & 7) == 0) {                        // XCD swizzle: band of h m-tiles/XCD
    int h = Mb >> 3;
    int xcd = f & 7, s = f >> 3;
    mb = xcd * h + (s % h);
    nb = s / h;
  } else {
    mb = f % Mb;
    nb = f / Mb;
  }
  const int m0 = mb * 256, n0 = nb * 256;

  const int tid = threadIdx.x;
  const int wid = tid >> 6, lane = tid & 63;
  const int lm = lane & 15, quad = lane >> 4;
  const int wr = wid >> 2, wc = wid & 3;      // 2x4 wave grid

  // staging source (per-lane, INVERSE-swizzled so the linear gload_lds dest
  // ends up swizzled): within a unit-part (128 rows x 32 k), thread t owns
  // row = t>>2, phys chunk = t&3, which must receive logical chunk
  // (t&3) ^ (row&3).
  const int srow = tid >> 2;                              // 0..127
  const int sk = (((tid & 3) ^ (srow & 3)) << 3);         // logical k elems
  const u16* pA = A + (size_t)(m0 + srow) * K_DIM + sk;
  const u16* pB = Bt + (size_t)(n0 + srow) * K_DIM + sk;
  const int ldst = wid * 512;                 // wave-uniform element base

  // read side: fragment row r, k-chunk quad -> phys chunk quad ^ (r&3),
  // r&3 == lm&3 for all fragments (row strides are multiples of 16).
  const int pc8 = (quad ^ (lm & 3)) << 3;
  const int rowAe = wr * 4096 + lm * 32 + pc8;            // + i*512
  const int rowBe = 8192 + wc * 2048 + lm * 32 + pc8;     // + j*512

  floatx4 acc[8][4] = {};
  short8 av[4], bv[4];

  // stage unit U (0/1) of the tile at pA/pB into buffer bufe_: 4 loads
  // (A rows 0-127, A rows 128-255, B rows 0-127, B rows 128-255)
#define STA(bufe_, U_)                                                         \
  do {                                                                         \
    async16(pA + (U_) * 32, &lds[(bufe_) + (U_) * 16384 + ldst]);              \
    async16(pA + 128 * (size_t)K_DIM + (U_) * 32,                              \
            &lds[(bufe_) + (U_) * 16384 + 4096 + ldst]);                       \
  } while (0)
#define STB(bufe_, U_)                                                         \
  do {                                                                         \
    async16(pB + (U_) * 32, &lds[(bufe_) + (U_) * 16384 + 8192 + ldst]);       \
    async16(pB + 128 * (size_t)K_DIM + (U_) * 32,                              \
            &lds[(bufe_) + (U_) * 16384 + 12288 + ldst]);                      \
  } while (0)

#define LDSA(i_, s_) \
  (*(const short8*)&lds[bcur + (s_) * 16384 + rowAe + (i_) * 512])
#define LDSB(j_, s_) \
  (*(const short8*)&lds[bcur + (s_) * 16384 + rowBe + (j_) * 512])
#define MFMA16(iofs_)                                                          \
  _Pragma("unroll") for (int i = 0; i < 4; ++i)                                \
  _Pragma("unroll") for (int j = 0; j < 4; ++j)                                \
      acc[(iofs_) + i][j] = __builtin_amdgcn_mfma_f32_16x16x32_bf16(           \
          av[i], bv[j], acc[(iofs_) + i][j], 0, 0, 0);
#define BAR() __builtin_amdgcn_s_barrier()
#define SCHED0() __builtin_amdgcn_sched_barrier(0)

  // prologue: stage tile 0, unit order U0 then U1 (8 loads)
  STA(0, 0); STB(0, 0);
  STA(0, 1); STB(0, 1);
  pA += 64; pB += 64;                         // pA/pB now point at tile 1

#pragma unroll 1
  for (int t = 0; t < NT - 1; ++t) {
    const int bcur = (t & 1) << 15;
    const int bnxt = bcur ^ 32768;

    // gate0: drain own oldest 4 loads (= t:U0); t:U1 stays in flight
    asm volatile("s_waitcnt vmcnt(4)" ::: "memory");
    BAR();
    SCHED0();

    // ph0: kstep 0, wave rows 0-63 ; issue t+1:U0 A-parts
#pragma unroll
    for (int j = 0; j < 4; ++j) bv[j] = LDSB(j, 0);
#pragma unroll
    for (int i = 0; i < 4; ++i) av[i] = LDSA(i, 0);
    STA(bnxt, 0);
    BAR();
    __builtin_amdgcn_s_setprio(1);
    MFMA16(0);
    __builtin_amdgcn_s_setprio(0);
    BAR();

    // ph1: kstep 0, wave rows 64-127 ; issue t+1:U0 B-parts
#pragma unroll
    for (int i = 0; i < 4; ++i) av[i] = LDSA(4 + i, 0);
    STB(bnxt, 0);
    BAR();
    __builtin_amdgcn_s_setprio(1);
    MFMA16(4);
    __builtin_amdgcn_s_setprio(0);
    BAR();

    // gate1: drain own next 4 (= t:U1); t+1:U0 (4) stays in flight
    asm volatile("s_waitcnt vmcnt(4)" ::: "memory");
    BAR();
    SCHED0();

    // ph2: kstep 1, wave rows 0-63 ; issue t+1:U1 A-parts
#pragma unroll
    for (int j = 0; j < 4; ++j) bv[j] = LDSB(j, 1);
#pragma unroll
    for (int i = 0; i < 4; ++i) av[i] = LDSA(i, 1);
    STA(bnxt, 1);
    BAR();
    __builtin_amdgcn_s_setprio(1);
    MFMA16(0);
    __builtin_amdgcn_s_setprio(0);
    BAR();

    // ph3: kstep 1, wave rows 64-127 ; issue t+1:U1 B-parts
#pragma unroll
    for (int i = 0; i < 4; ++i) av[i] = LDSA(4 + i, 1);
    STB(bnxt, 1);
    BAR();
    __builtin_amdgcn_s_setprio(1);
    MFMA16(4);
    __builtin_amdgcn_s_setprio(0);
    SCHED0();
    BAR();  // end-of-tile

    pA += 64;
    pB += 64;
  }

  // peeled final tile: drain all loads, no prefetch
  {
    const int bcur = ((NT - 1) & 1) << 15;
    asm volatile("s_waitcnt vmcnt(0)" ::: "memory");
    BAR();
    SCHED0();
#pragma unroll
    for (int j = 0; j < 4; ++j) bv[j] = LDSB(j, 0);
#pragma unroll
    for (int i = 0; i < 4; ++i) av[i] = LDSA(i, 0);
    MFMA16(0);
#pragma unroll
    for (int i = 0; i < 4; ++i) av[i] = LDSA(4 + i, 0);
    MFMA16(4);
#pragma unroll
    for (int j = 0; j < 4; ++j) bv[j] = LDSB(j, 1);
#pragma unroll
    for (int i = 0; i < 4; ++i) av[i] = LDSA(i, 1);
    MFMA16(0);
#pragma unroll
    for (int i = 0; i < 4; ++i) av[i] = LDSA(4 + i, 1);
    MFMA16(4);
  }

  // epilogue: C/D layout col=lane&15, row=quad*4+reg
  const int colb = n0 + wc * 64 + lm;
  const int row0 = m0 + wr * 128 + quad * 4;
#pragma unroll
  for (int j = 0; j < 4; ++j) {
    float bj = bias[colb + j * 16];
#pragma unroll
    for (int i = 0; i < 8; ++i) {
      int r0 = row0 + i * 16;
#pragma unroll
      for (int r = 0; r < 4; ++r)
        out[(size_t)(r0 + r) * N_DIM + colb + j * 16] = acc[i][j][r] + bj;
    }
  }
#undef STA
#undef STB
#undef LDSA
#undef LDSB
#undef MFMA16
#undef BAR
#undef SCHED0
}

// ---------------------------------------------------------------------------
// previous 128x128 gemm kept as fallback for M%256!=0 (but M%128==0)
__global__ __launch_bounds__(256) void gemm_bf16(
    const u16* __restrict__ A, const u16* __restrict__ Bt,
    const float* __restrict__ bias, float* __restrict__ out, int Mb) {
  constexpr int BK = 32;
  __shared__ __align__(16) u16 As[128 * BK];  // 8KB
  __shared__ __align__(16) u16 Bs[128 * BK];  // 8KB

  const int f = blockIdx.x;
  int mb, nb;
  if ((Mb & 7) == 0) {
    int h = Mb >> 3;
    int xcd = f & 7;
    int s = f >> 3;
    mb = xcd * h + (s % h);
    nb = s / h;
  } else {
    mb = f % Mb;
    nb = f / Mb;
  }
  const int m0 = mb * 128;
  const int n0 = nb * 128;

  const int tid = threadIdx.x;
  const int wave = tid >> 6;
  const int lane = tid & 63;
  const int lm = lane & 15;
  const int quad = lane >> 4;
  const int wm = (wave & 1) * 64;
  const int wn = (wave >> 1) * 64;

  const int c0 = tid, c1 = tid + 256;
  const u16* gA0 = A + (size_t)(m0 + (c0 >> 2)) * K_DIM + (c0 & 3) * 8;
  const u16* gA1 = A + (size_t)(m0 + (c1 >> 2)) * K_DIM + (c1 & 3) * 8;
  const u16* gB0 = Bt + (size_t)(n0 + (c0 >> 2)) * K_DIM + (c0 & 3) * 8;
  const u16* gB1 = Bt + (size_t)(n0 + (c1 >> 2)) * K_DIM + (c1 & 3) * 8;
  u16* lA0 = As + (wave * 64) * 8;
  u16* lA1 = As + (256 + wave * 64) * 8;
  u16* lB0 = Bs + (wave * 64) * 8;
  u16* lB1 = Bs + (256 + wave * 64) * 8;

  floatx4 acc[4][4] = {};

  for (int k0i = 0; k0i < K_DIM; k0i += BK) {
    async16(gA0, lA0);
    async16(gA1, lA1);
    async16(gB0, lB0);
    async16(gB1, lB1);
    gA0 += BK; gA1 += BK; gB0 += BK; gB1 += BK;
    __syncthreads();

    short8 af[4], bfr[4];
#pragma unroll
    for (int i = 0; i < 4; i++)
      af[i] = *(const short8*)&As[(wm + i * 16 + lm) * BK + quad * 8];
#pragma unroll
    for (int j = 0; j < 4; j++)
      bfr[j] = *(const short8*)&Bs[(wn + j * 16 + lm) * BK + quad * 8];
#pragma unroll
    for (int i = 0; i < 4; i++)
#pragma unroll
      for (int j = 0; j < 4; j++)
        acc[i][j] = __builtin_amdgcn_mfma_f32_16x16x32_bf16(af[i], bfr[j],
                                                            acc[i][j], 0, 0, 0);
    __syncthreads();
  }

  const int colb = n0 + wn + lm;
#pragma unroll
  for (int j = 0; j < 4; j++) {
    float bj = bias[colb + j * 16];
#pragma unroll
    for (int i = 0; i < 4; i++) {
      int row = m0 + wm + i * 16 + quad * 4;
#pragma unroll
      for (int r = 0; r < 4; r++)
        out[(size_t)(row + r) * N_DIM + colb + j * 16] = acc[i][j][r] + bj;
    }
  }
}

// ---------------------------------------------------------------------------
// fallback (only if workspace too small): 1 thread / output, fp32
__global__ void naive_gemm(const float* __restrict__ x, const int* __restrict__ qw,
                           const int* __restrict__ qz, const float* __restrict__ sc,
                           const float* __restrict__ bias, float* __restrict__ out,
                           int M) {
  long long idx = (long long)blockIdx.x * 256 + threadIdx.x;
  if (idx >= (long long)M * N_DIM) return;
  int m = (int)(idx / N_DIM);
  int n = (int)(idx % N_DIM);
  int p = n >> 3, j = n & 7;
  int sh = ((j & 1) << 4) | ((j >> 1) << 2);
  float acc = 0.f;
  for (int g = 0; g < NGRP; g++) {
    float s = sc[(size_t)g * N_DIM + n];
    int z = (qz[g * NPACK + p] >> sh) & 15;
    float part = 0.f;
    for (int kk = 0; kk < GSIZE; kk++) {
      int k = g * GSIZE + kk;
      int w = ((qw[(size_t)k * NPACK + p] >> sh) & 15) - z;
      part += x[(size_t)m * K_DIM + k] * (float)w;
    }
    acc += part * s;
  }
  out[idx] = acc + bias[n];
}

// ---------------------------------------------------------------------------
extern "C" void kernel_launch(void* const* d_in, const int* in_sizes, int n_in,
                              void* d_out, int out_size, void* d_ws, size_t ws_size,
                              hipStream_t stream) {
  const float* x = (const float*)d_in[0];
  const int* qw = (const int*)d_in[1];
  const int* qz = (const int*)d_in[2];
  const float* sc = (const float*)d_in[3];
  const float* bias = (const float*)d_in[4];
  float* out = (float*)d_out;
  const int M = in_sizes[0] / K_DIM;  // 4096 (B*S)

  size_t xb_bytes = (size_t)M * K_DIM * 2;           // 33.5 MB
  size_t wt_bytes = (size_t)K_DIM * N_DIM * 2;       // 90.2 MB

  if (ws_size >= xb_bytes + wt_bytes && (M % 128) == 0) {
    u16* xb = (u16*)d_ws;
    u16* Wt = (u16*)((char*)d_ws + xb_bytes);
    int cvt_blocks = (M * (K_DIM / 8)) / 256;        // exact: M%128==0
    cvt_x_bf16<<<cvt_blocks, 256, 0, stream>>>(x, xb);
    dequant_wt<<<dim3(NPACK / 32, K_DIM / 128), 256, 0, stream>>>(qw, qz, sc, Wt);
    if ((M % 256) == 0) {
      int Mb = M / 256;
      gemm_bf16_256<<<dim3(Mb * (N_DIM / 256)), 512, 0, stream>>>(xb, Wt, bias,
                                                                  out, Mb);
    } else {
      int Mb = M / 128;
      gemm_bf16<<<dim3(Mb * (N_DIM / 128)), 256, 0, stream>>>(xb, Wt, bias, out,
                                                              Mb);
    }
  } else {
    long long total = (long long)M * N_DIM;
    naive_gemm<<<(int)((total + 255) / 256), 256, 0, stream>>>(x, qw, qz, sc, bias,
                                                               out, M);
  }
}